// Round 4
// baseline (166.940 us; speedup 1.0000x reference)
//
#include <hip/hip_runtime.h>
#include <math.h>

typedef float f32x4_t __attribute__((ext_vector_type(4)));
typedef short bf16x8_t __attribute__((ext_vector_type(8)));

#define B_   8
#define C_   512
#define T_   1024
#define NH_  8
#define CH_  64
#define EPSF 1e-5f

#define MFMA16(a, b, c) __builtin_amdgcn_mfma_f32_16x16x32_bf16((a), (b), (c), 0, 0, 0)

// Direct global->LDS 16B copy. LDS dest is wave-uniform base + lane*16.
#define GLD16(gp, lp) __builtin_amdgcn_global_load_lds( \
    (const __attribute__((address_space(1))) unsigned int*)(gp), \
    (__attribute__((address_space(3))) unsigned int*)(lp), 16, 0, 0)

__device__ __forceinline__ unsigned short f2bf(float f) {
  union { float f; unsigned u; } v; v.f = f;
  unsigned r = v.u + 0x7FFFu + ((v.u >> 16) & 1u);
  return (unsigned short)(r >> 16);
}

// ---------------------------------------------------------------------------
// Fused: blocks 0..255 do GroupNorm -> xnT[b][t][c] bf16; blocks 256.. do
// fp32->bf16 weight conversion. GN stages the 64KB group slice in LDS during
// the sum pass so x is read from HBM exactly once.
// ---------------------------------------------------------------------------
__global__ __launch_bounds__(256) void prep_gn_kernel(
    const float* __restrict__ x, const float* __restrict__ w,
    const float* __restrict__ bvec, unsigned short* __restrict__ xnT,
    const float* __restrict__ qw_f, const float* __restrict__ pw_f,
    unsigned short* __restrict__ qw, unsigned short* __restrict__ pw)
{
  __shared__ __align__(16) float xs[16 * 1024];   // 64 KB group slice
  __shared__ float rs_[4], r2_[4];
  __shared__ float mu_s, rsig_s;

  int tid = threadIdx.x;
  if (blockIdx.x >= 256) {
    int idx = (blockIdx.x - 256) * 256 + tid;    // float4 granularity
    const int N1 = 1536 * 512 / 4;
    const int N2 = 512 * 512 / 4;
    if (idx < N1) {
      float4 v = ((const float4*)qw_f)[idx];
      uint2 o;
      o.x = (unsigned)f2bf(v.x) | ((unsigned)f2bf(v.y) << 16);
      o.y = (unsigned)f2bf(v.z) | ((unsigned)f2bf(v.w) << 16);
      ((uint2*)qw)[idx] = o;
    } else if (idx < N1 + N2) {
      int j = idx - N1;
      float4 v = ((const float4*)pw_f)[j];
      uint2 o;
      o.x = (unsigned)f2bf(v.x) | ((unsigned)f2bf(v.y) << 16);
      o.y = (unsigned)f2bf(v.z) | ((unsigned)f2bf(v.w) << 16);
      ((uint2*)pw)[j] = o;
    }
    return;
  }

  int blk = blockIdx.x;            // b*32 + g
  int b = blk >> 5, g = blk & 31;
  const float* xp = x + ((size_t)(b * C_ + g * 16)) * T_;
  const int N = 16 * T_;           // 16384

  float s = 0.f, s2 = 0.f;
  for (int i = tid * 4; i < N; i += 256 * 4) {
    float4 v = *(const float4*)(xp + i);
    *(float4*)&xs[i] = v;                          // stash for pass 2
    s  += v.x + v.y + v.z + v.w;
    s2 += v.x * v.x + v.y * v.y + v.z * v.z + v.w * v.w;
  }
  for (int off = 32; off; off >>= 1) {
    s  += __shfl_down(s,  off, 64);
    s2 += __shfl_down(s2, off, 64);
  }
  int wid = tid >> 6, lane = tid & 63;
  if (lane == 0) { rs_[wid] = s; r2_[wid] = s2; }
  __syncthreads();
  if (tid == 0) {
    float ts = rs_[0] + rs_[1] + rs_[2] + rs_[3];
    float t2 = r2_[0] + r2_[1] + r2_[2] + r2_[3];
    float mu = ts / (float)N;
    float var = t2 / (float)N - mu * mu;
    mu_s = mu;
    rsig_s = rsqrtf(var + EPSF);
  }
  __syncthreads();
  float mu = mu_s, rs = rsig_s;

  float wl[16], bl[16];
  for (int c = 0; c < 16; ++c) { wl[c] = w[g * 16 + c]; bl[c] = bvec[g * 16 + c]; }

  for (int t = tid; t < T_; t += 256) {
    unsigned short buf[16] __attribute__((aligned(16)));
    for (int c = 0; c < 16; ++c) {
      float val = xs[c * T_ + t];                  // LDS, conflict-free
      buf[c] = f2bf((val - mu) * rs * wl[c] + bl[c]);
    }
    unsigned short* dst = xnT + ((size_t)b * T_ + t) * C_ + g * 16;
    *(uint4*)dst       = *(uint4*)buf;
    *(uint4*)(dst + 8) = *(uint4*)(buf + 8);
  }
}

// ---------------------------------------------------------------------------
// QKV GEMM (bf16 MFMA), global_load_lds staging, 2-phase dbuf, 1 barrier/K.
// A = weight [o][c] (k-contig), B = xnT [t][c] (k-contig).
// ---------------------------------------------------------------------------
__global__ __launch_bounds__(256) void gemm_qkv_kernel(
    const unsigned short* __restrict__ W, const unsigned short* __restrict__ xnT,
    const float* __restrict__ bias,
    unsigned short* __restrict__ q_t, unsigned short* __restrict__ k_t,
    unsigned short* __restrict__ v_c)
{
  int b = blockIdx.z;
  int m0 = blockIdx.y * 128, n0 = blockIdx.x * 128;
  int tid = threadIdx.x;
  int w = tid >> 6, lane = tid & 63, quad = lane >> 4, lr = lane & 15;
  int wm = w >> 1, wn = w & 1;

  __shared__ __align__(16) unsigned short Asl[2][128][32];
  __shared__ __align__(16) unsigned short Bsl[2][128][32];

  f32x4_t acc[4][4];
  for (int i = 0; i < 4; ++i)
    for (int j = 0; j < 4; ++j) acc[i][j] = (f32x4_t){0.f, 0.f, 0.f, 0.f};

  int ur = tid >> 2, uk = (tid & 3) * 8;
  const unsigned short* Ap = W + (size_t)(m0 + ur) * C_ + uk;
  const unsigned short* Bp = xnT + ((size_t)b * T_ + n0 + ur) * C_ + uk;

#define STAGE_QKV(buf, k0)                                        \
  do {                                                            \
    GLD16(Ap + (k0),            &Asl[buf][w * 16][0]);            \
    GLD16(Ap + 64 * C_ + (k0),  &Asl[buf][64 + w * 16][0]);       \
    GLD16(Bp + (k0),            &Bsl[buf][w * 16][0]);            \
    GLD16(Bp + 64 * C_ + (k0),  &Bsl[buf][64 + w * 16][0]);       \
  } while (0)

  STAGE_QKV(0, 0);
  __syncthreads();                       // vmcnt(0) drain: buf0 ready

  int cur = 0;
  for (int k0 = 0; k0 < C_; k0 += 32) {
    if (k0 + 32 < C_) STAGE_QKV(cur ^ 1, k0 + 32);
    bf16x8_t af[4], bfv[4];
    for (int i = 0; i < 4; ++i) af[i]  = *(bf16x8_t*)&Asl[cur][wm * 64 + i * 16 + lr][quad * 8];
    for (int j = 0; j < 4; ++j) bfv[j] = *(bf16x8_t*)&Bsl[cur][wn * 64 + j * 16 + lr][quad * 8];
    for (int i = 0; i < 4; ++i)
      for (int j = 0; j < 4; ++j)
        acc[i][j] = MFMA16(af[i], bfv[j], acc[i][j]);
    __syncthreads();                     // drains staged loads + frag reads
    cur ^= 1;
  }
#undef STAGE_QKV

  for (int i = 0; i < 4; ++i) {
    int ob = m0 + wm * 64 + i * 16 + quad * 4;
    int h = ob / 192, r0 = ob % 192;
    for (int j = 0; j < 4; ++j) {
      int t = n0 + wn * 64 + j * 16 + lr;
      if (r0 < 128) {
        unsigned short pk[4] __attribute__((aligned(8)));
      #pragma unroll
        for (int r = 0; r < 4; ++r) pk[r] = f2bf(acc[i][j][r] + bias[ob + r]);
        unsigned short* base = (r0 < 64) ? q_t : k_t;
        int chn = (r0 < 64) ? r0 : r0 - 64;
        *(uint2*)&base[((size_t)(b * NH_ + h) * T_ + t) * CH_ + chn] = *(uint2*)pk;
      } else {
      #pragma unroll
        for (int r = 0; r < 4; ++r) {
          float vv = acc[i][j][r] + bias[ob + r];
          v_c[((size_t)(b * NH_ + h) * CH_ + (r0 - 128 + r)) * T_ + t] = f2bf(vv);
        }
      }
    }
  }
}

// ---------------------------------------------------------------------------
// Flash attention v4: V fragments read DIRECTLY from global (L2-resident,
// 2MB/XCD working set) -> v_s staging and V ds_reads eliminated. Q frags
// loaded once from global (q_s eliminated); output staged through p_s.
// LDS bytes/wave/iter: 28KB -> 18KB (K-frags 8 + P-write 4 + P-read 4 +
// K-staging 2). LDS total 27KB -> 3+ blocks/CU (was 2). K prefetch issued
// after the staging barrier -> full-iter latency hiding.
// Swapped QK^T (mfma(K,Q)), fixed-shift softmax, in-register row-sum.
// ---------------------------------------------------------------------------
__global__ __launch_bounds__(256) void attn_kernel(
    const unsigned short* __restrict__ q_t, const unsigned short* __restrict__ k_t,
    const unsigned short* __restrict__ v_c, unsigned short* __restrict__ a_t)
{
  int bh = blockIdx.x;
  int t0 = blockIdx.y * 128;
  int tid = threadIdx.x;
  int w = tid >> 6, lane = tid & 63, quad = lane >> 4, lr = lane & 15;

  __shared__ __align__(16) unsigned short k_s[64][72];
  __shared__ __align__(16) unsigned short p_s[128][72];

  int r0 = tid >> 3, c0 = (tid & 7) * 8;    // staging: 32 rows x 64 cols/chunk

  // Q fragments direct from global: t = t0 + w*32 + rb*16 + lr, ch = kk*32+quad*8
  bf16x8_t bq[2][2];
#pragma unroll
  for (int rb = 0; rb < 2; ++rb)
#pragma unroll
    for (int kk = 0; kk < 2; ++kk)
      bq[rb][kk] = *(const bf16x8_t*)
          &q_t[((size_t)bh * T_ + t0 + w * 32 + rb * 16 + lr) * CH_ + kk * 32 + quad * 8];

  // K tile 0 prefetch into regs
  uint4 kr0 = *(const uint4*)&k_t[((size_t)bh * T_ + r0) * CH_ + c0];
  uint4 kr1 = *(const uint4*)&k_t[((size_t)bh * T_ + r0 + 32) * CH_ + c0];

  // V per-thread base: frag elem e -> V[ch = j*16+lr][s = s0 + kk*32 + quad*8 + e]
  const unsigned short* vbase = v_c + ((size_t)bh * CH_ + lr) * T_ + quad * 8;

  f32x4_t o_acc[2][4];
#pragma unroll
  for (int rb = 0; rb < 2; ++rb)
    for (int j = 0; j < 4; ++j) o_acc[rb][j] = (f32x4_t){0.f, 0.f, 0.f, 0.f};
  float l_sum[2] = {0.f, 0.f};     // rowsum for t = w*32 + rb*16 + lr

  const float SCL = 0.18033688f;   // 0.125 * log2(e)
  const float MSH = 11.541560f;    // 8 * log2(e)  (fixed softmax shift)

  for (int s0 = 0; s0 < T_; s0 += 64) {
    __syncthreads();               // all reads of k_s from prev iter done
    *(uint4*)&k_s[r0][c0]      = kr0;
    *(uint4*)&k_s[r0 + 32][c0] = kr1;
    __syncthreads();               // k_s ready
    if (s0 + 64 < T_) {            // next-K prefetch: drains at NEXT iter's
      kr0 = *(const uint4*)&k_t[((size_t)bh * T_ + s0 + 64 + r0) * CH_ + c0];
      kr1 = *(const uint4*)&k_t[((size_t)bh * T_ + s0 + 96 + r0) * CH_ + c0];
    }                              // barrier -> full-iter latency hiding

    // V fragment loads for this tile (L2); issued early, used in PV
    bf16x8_t bvv[4][2];
#pragma unroll
    for (int j = 0; j < 4; ++j)
#pragma unroll
      for (int kk = 0; kk < 2; ++kk)
        bvv[j][kk] = *(const bf16x8_t*)(vbase + (size_t)j * 16 * T_ + s0 + kk * 32);

    // Swapped QK^T + softmax, per j (short sc live range):
    // C[s][t]: thread (quad,lr) holds s = j*16 + quad*4 + r, t = w*32+rb*16+lr
#pragma unroll
    for (int j = 0; j < 4; ++j) {
      bf16x8_t ak0 = *(bf16x8_t*)&k_s[j * 16 + lr][quad * 8];
      bf16x8_t ak1 = *(bf16x8_t*)&k_s[j * 16 + lr][32 + quad * 8];
      f32x4_t a0 = (f32x4_t){0.f, 0.f, 0.f, 0.f};
      f32x4_t a1 = (f32x4_t){0.f, 0.f, 0.f, 0.f};
      a0 = MFMA16(ak0, bq[0][0], a0);
      a0 = MFMA16(ak1, bq[0][1], a0);
      a1 = MFMA16(ak0, bq[1][0], a1);
      a1 = MFMA16(ak1, bq[1][1], a1);
#pragma unroll
      for (int rb = 0; rb < 2; ++rb) {
        const f32x4_t& av = rb ? a1 : a0;
        unsigned u[4];
        float rsum = 0.f;
#pragma unroll
        for (int r = 0; r < 4; ++r) {
          union { float f; unsigned v; } cv;
          cv.f = __builtin_amdgcn_exp2f(av[r] * SCL - MSH);
          u[r] = cv.v & 0xFFFF0000u;             // truncated-bf16 as fp32 bits
          union { unsigned v; float f; } rf; rf.v = u[r];
          rsum += rf.f;
        }
        uint2 pk;
        pk.x = (u[0] >> 16) | u[1];
        pk.y = (u[2] >> 16) | u[3];
        *(uint2*)&p_s[w * 32 + rb * 16 + lr][j * 16 + quad * 4] = pk;
        l_sum[rb] += rsum;
      }
    }
    // reduce rowsums over quads (this iter's contributions were added per j;
    // quad-reduce once per iter): bits 4,5 of lane
#pragma unroll
    for (int rb = 0; rb < 2; ++rb) {
      // subtract nothing: l_sum holds running total incl. prev iters (already
      // fully reduced); reduce only this iter's partial via associativity:
      // we instead reduce the per-iter partials implicitly -- sum is linear,
      // so reducing the TOTAL each iter would double-count. Handle by
      // reducing only at the end: see below. (no-op here)
    }

    // wave-local roundtrip: wave w wrote rows w*32..w*32+31, reads the same
    bf16x8_t ap[2][2];
#pragma unroll
    for (int rb = 0; rb < 2; ++rb) {
      ap[rb][0] = *(bf16x8_t*)&p_s[w * 32 + rb * 16 + lr][quad * 8];
      ap[rb][1] = *(bf16x8_t*)&p_s[w * 32 + rb * 16 + lr][32 + quad * 8];
    }

    __builtin_amdgcn_s_setprio(1);
#pragma unroll
    for (int j = 0; j < 4; ++j)
#pragma unroll
      for (int kk = 0; kk < 2; ++kk) {
        o_acc[0][j] = MFMA16(ap[0][kk], bvv[j][kk], o_acc[0][j]);
        o_acc[1][j] = MFMA16(ap[1][kk], bvv[j][kk], o_acc[1][j]);
      }
    __builtin_amdgcn_s_setprio(0);
  }

  // final rowsum reduce over quads (l_sum accumulated per-thread partials:
  // each thread summed its 4 s-values per j per iter -> per-thread partial
  // covers s = {16j + quad*4 + r}; quad-reduce completes the row)
#pragma unroll
  for (int rb = 0; rb < 2; ++rb) {
    l_sum[rb] += __shfl_xor(l_sum[rb], 16, 64);
    l_sum[rb] += __shfl_xor(l_sum[rb], 32, 64);
  }

  // normalize + stage output via p_s (reuse), then coalesced store
#pragma unroll
  for (int rb = 0; rb < 2; ++rb) {
#pragma unroll
    for (int r = 0; r < 4; ++r) {
      float lv = __shfl(l_sum[rb], quad * 4 + r, 64);
      float inv = 1.f / lv;
#pragma unroll
      for (int j = 0; j < 4; ++j)
        p_s[w * 32 + rb * 16 + quad * 4 + r][j * 16 + lr] = f2bf(o_acc[rb][j][r] * inv);
    }
  }
  __syncthreads();
#pragma unroll
  for (int cch = 0; cch < 4; ++cch)
    *(uint4*)&a_t[((size_t)bh * T_ + t0 + r0 + 32 * cch) * CH_ + c0] =
        *(uint4*)&p_s[r0 + 32 * cch][c0];
}

// ---------------------------------------------------------------------------
// Proj GEMM (bf16 MFMA) + bias + fp32 residual -> d_out [b][o][t]
// global_load_lds staging, 2-phase dbuf, 1 barrier/K.
// ---------------------------------------------------------------------------
__global__ __launch_bounds__(256) void gemm_proj_kernel(
    const unsigned short* __restrict__ W, const unsigned short* __restrict__ a_t,
    const float* __restrict__ bias, const float* __restrict__ xres,
    float* __restrict__ out)
{
  int b = blockIdx.z;
  int m0 = blockIdx.y * 128, n0 = blockIdx.x * 128;
  int tid = threadIdx.x;
  int w = tid >> 6, lane = tid & 63, quad = lane >> 4, lr = lane & 15;
  int wm = w >> 1, wn = w & 1;

  __shared__ __align__(16) unsigned short Asl[2][128][32];
  __shared__ __align__(16) unsigned short Bsl[2][128][32];

  f32x4_t acc[4][4];
  for (int i = 0; i < 4; ++i)
    for (int j = 0; j < 4; ++j) acc[i][j] = (f32x4_t){0.f, 0.f, 0.f, 0.f};

  int ur = tid >> 2, uk = (tid & 3) * 8;
  const unsigned short* Ap = W + (size_t)(m0 + ur) * C_ + uk;

#define STAGE_PROJ(buf, k0)                                                   \
  do {                                                                        \
    const unsigned short* Bp = a_t +                                          \
        ((size_t)(b * NH_ + ((k0) >> 6)) * T_ + n0 + ur) * CH_ + ((k0) & 63) + uk; \
    GLD16(Ap + (k0),           &Asl[buf][w * 16][0]);                         \
    GLD16(Ap + 64 * C_ + (k0), &Asl[buf][64 + w * 16][0]);                    \
    GLD16(Bp,                  &Bsl[buf][w * 16][0]);                         \
    GLD16(Bp + 64 * CH_,       &Bsl[buf][64 + w * 16][0]);                    \
  } while (0)

  STAGE_PROJ(0, 0);
  __syncthreads();

  int cur = 0;
  for (int k0 = 0; k0 < C_; k0 += 32) {
    if (k0 + 32 < C_) STAGE_PROJ(cur ^ 1, k0 + 32);
    bf16x8_t af[4], bfv[4];
    for (int i = 0; i < 4; ++i) af[i]  = *(bf16x8_t*)&Asl[cur][wm * 64 + i * 16 + lr][quad * 8];
    for (int j = 0; j < 4; ++j) bfv[j] = *(bf16x8_t*)&Bsl[cur][wn * 64 + j * 16 + lr][quad * 8];
    for (int i = 0; i < 4; ++i)
      for (int j = 0; j < 4; ++j)
        acc[i][j] = MFMA16(af[i], bfv[j], acc[i][j]);
    __syncthreads();
    cur ^= 1;
  }
#undef STAGE_PROJ

  for (int i = 0; i < 4; ++i) {
    int ob = m0 + wm * 64 + i * 16 + quad * 4;
    for (int j = 0; j < 4; ++j) {
      int t = n0 + wn * 64 + j * 16 + lr;
    #pragma unroll
      for (int r = 0; r < 4; ++r) {
        size_t idx = ((size_t)(b * C_ + ob + r)) * T_ + t;
        out[idx] = acc[i][j][r] + bias[ob + r] + xres[idx];
      }
    }
  }
}

// ---------------------------------------------------------------------------
extern "C" void kernel_launch(void* const* d_in, const int* in_sizes, int n_in,
                              void* d_out, int out_size, void* d_ws, size_t ws_size,
                              hipStream_t stream)
{
  const float* x      = (const float*)d_in[0];
  const float* norm_w = (const float*)d_in[1];
  const float* norm_b = (const float*)d_in[2];
  const float* qkv_w  = (const float*)d_in[3];
  const float* qkv_b  = (const float*)d_in[4];
  const float* proj_w = (const float*)d_in[5];
  const float* proj_b = (const float*)d_in[6];
  float* out = (float*)d_out;

  char* ws = (char*)d_ws;
  unsigned short* qw  = (unsigned short*)ws;                       // 1.5 MiB
  unsigned short* pw  = (unsigned short*)(ws + 1572864);           // 0.5 MiB
  unsigned short* xnT = (unsigned short*)(ws + 2097152);           // 8 MiB
  unsigned short* q_t = (unsigned short*)(ws + 10485760);          // 8 MiB
  unsigned short* k_t = (unsigned short*)(ws + 18874368);          // 8 MiB
  unsigned short* v_c = (unsigned short*)(ws + 27262976);          // 8 MiB
  unsigned short* a_t = (unsigned short*)(ws + 35651584);          // 8 MiB

  prep_gn_kernel<<<dim3(256 + 1024), dim3(256), 0, stream>>>(
      x, norm_w, norm_b, xnT, qkv_w, proj_w, qw, pw);

  gemm_qkv_kernel<<<dim3(T_ / 128, 1536 / 128, B_), dim3(256), 0, stream>>>(
      qw, xnT, qkv_b, q_t, k_t, v_c);

  attn_kernel<<<dim3(B_ * NH_, T_ / 128), dim3(256), 0, stream>>>(q_t, k_t, v_c, a_t);

  gemm_proj_kernel<<<dim3(T_ / 128, C_ / 128, B_), dim3(256), 0, stream>>>(
      pw, a_t, proj_b, x, out);
}

// Round 5
// 164.571 us; speedup vs baseline: 1.0144x; 1.0144x over previous
//
#include <hip/hip_runtime.h>
#include <math.h>

typedef float f32x4_t __attribute__((ext_vector_type(4)));
typedef short bf16x8_t __attribute__((ext_vector_type(8)));

#define B_   8
#define C_   512
#define T_   1024
#define NH_  8
#define CH_  64
#define EPSF 1e-5f

#define MFMA16(a, b, c) __builtin_amdgcn_mfma_f32_16x16x32_bf16((a), (b), (c), 0, 0, 0)

// Direct global->LDS 16B copy. LDS dest is wave-uniform base + lane*16.
#define GLD16(gp, lp) __builtin_amdgcn_global_load_lds( \
    (const __attribute__((address_space(1))) unsigned int*)(gp), \
    (__attribute__((address_space(3))) unsigned int*)(lp), 16, 0, 0)

__device__ __forceinline__ unsigned short f2bf(float f) {
  union { float f; unsigned u; } v; v.f = f;
  unsigned r = v.u + 0x7FFFu + ((v.u >> 16) & 1u);
  return (unsigned short)(r >> 16);
}

// ---------------------------------------------------------------------------
// Fused: blocks 0..255 do GroupNorm -> xnT[b][t][c] bf16; blocks 256.. do
// fp32->bf16 weight conversion. GN stages the 64KB group slice in LDS during
// the sum pass so x is read from HBM exactly once.
// ---------------------------------------------------------------------------
__global__ __launch_bounds__(256) void prep_gn_kernel(
    const float* __restrict__ x, const float* __restrict__ w,
    const float* __restrict__ bvec, unsigned short* __restrict__ xnT,
    const float* __restrict__ qw_f, const float* __restrict__ pw_f,
    unsigned short* __restrict__ qw, unsigned short* __restrict__ pw)
{
  __shared__ __align__(16) float xs[16 * 1024];   // 64 KB group slice
  __shared__ float rs_[4], r2_[4];
  __shared__ float mu_s, rsig_s;

  int tid = threadIdx.x;
  if (blockIdx.x >= 256) {
    int idx = (blockIdx.x - 256) * 256 + tid;    // float4 granularity
    const int N1 = 1536 * 512 / 4;
    const int N2 = 512 * 512 / 4;
    if (idx < N1) {
      float4 v = ((const float4*)qw_f)[idx];
      uint2 o;
      o.x = (unsigned)f2bf(v.x) | ((unsigned)f2bf(v.y) << 16);
      o.y = (unsigned)f2bf(v.z) | ((unsigned)f2bf(v.w) << 16);
      ((uint2*)qw)[idx] = o;
    } else if (idx < N1 + N2) {
      int j = idx - N1;
      float4 v = ((const float4*)pw_f)[j];
      uint2 o;
      o.x = (unsigned)f2bf(v.x) | ((unsigned)f2bf(v.y) << 16);
      o.y = (unsigned)f2bf(v.z) | ((unsigned)f2bf(v.w) << 16);
      ((uint2*)pw)[j] = o;
    }
    return;
  }

  int blk = blockIdx.x;            // b*32 + g
  int b = blk >> 5, g = blk & 31;
  const float* xp = x + ((size_t)(b * C_ + g * 16)) * T_;
  const int N = 16 * T_;           // 16384

  float s = 0.f, s2 = 0.f;
  for (int i = tid * 4; i < N; i += 256 * 4) {
    float4 v = *(const float4*)(xp + i);
    *(float4*)&xs[i] = v;                          // stash for pass 2
    s  += v.x + v.y + v.z + v.w;
    s2 += v.x * v.x + v.y * v.y + v.z * v.z + v.w * v.w;
  }
  for (int off = 32; off; off >>= 1) {
    s  += __shfl_down(s,  off, 64);
    s2 += __shfl_down(s2, off, 64);
  }
  int wid = tid >> 6, lane = tid & 63;
  if (lane == 0) { rs_[wid] = s; r2_[wid] = s2; }
  __syncthreads();
  if (tid == 0) {
    float ts = rs_[0] + rs_[1] + rs_[2] + rs_[3];
    float t2 = r2_[0] + r2_[1] + r2_[2] + r2_[3];
    float mu = ts / (float)N;
    float var = t2 / (float)N - mu * mu;
    mu_s = mu;
    rsig_s = rsqrtf(var + EPSF);
  }
  __syncthreads();
  float mu = mu_s, rs = rsig_s;

  float wl[16], bl[16];
  for (int c = 0; c < 16; ++c) { wl[c] = w[g * 16 + c]; bl[c] = bvec[g * 16 + c]; }

  for (int t = tid; t < T_; t += 256) {
    unsigned short buf[16] __attribute__((aligned(16)));
    for (int c = 0; c < 16; ++c) {
      float val = xs[c * T_ + t];                  // LDS, conflict-free
      buf[c] = f2bf((val - mu) * rs * wl[c] + bl[c]);
    }
    unsigned short* dst = xnT + ((size_t)b * T_ + t) * C_ + g * 16;
    *(uint4*)dst       = *(uint4*)buf;
    *(uint4*)(dst + 8) = *(uint4*)(buf + 8);
  }
}

// ---------------------------------------------------------------------------
// QKV GEMM (bf16 MFMA), global_load_lds staging, 2-phase dbuf, 1 barrier/K.
// A = weight [o][c] (k-contig), B = xnT [t][c] (k-contig).
// ---------------------------------------------------------------------------
__global__ __launch_bounds__(256) void gemm_qkv_kernel(
    const unsigned short* __restrict__ W, const unsigned short* __restrict__ xnT,
    const float* __restrict__ bias,
    unsigned short* __restrict__ q_t, unsigned short* __restrict__ k_t,
    unsigned short* __restrict__ v_c)
{
  int b = blockIdx.z;
  int m0 = blockIdx.y * 128, n0 = blockIdx.x * 128;
  int tid = threadIdx.x;
  int w = tid >> 6, lane = tid & 63, quad = lane >> 4, lr = lane & 15;
  int wm = w >> 1, wn = w & 1;

  __shared__ __align__(16) unsigned short Asl[2][128][32];
  __shared__ __align__(16) unsigned short Bsl[2][128][32];

  f32x4_t acc[4][4];
  for (int i = 0; i < 4; ++i)
    for (int j = 0; j < 4; ++j) acc[i][j] = (f32x4_t){0.f, 0.f, 0.f, 0.f};

  int ur = tid >> 2, uk = (tid & 3) * 8;
  const unsigned short* Ap = W + (size_t)(m0 + ur) * C_ + uk;
  const unsigned short* Bp = xnT + ((size_t)b * T_ + n0 + ur) * C_ + uk;

#define STAGE_QKV(buf, k0)                                        \
  do {                                                            \
    GLD16(Ap + (k0),            &Asl[buf][w * 16][0]);            \
    GLD16(Ap + 64 * C_ + (k0),  &Asl[buf][64 + w * 16][0]);       \
    GLD16(Bp + (k0),            &Bsl[buf][w * 16][0]);            \
    GLD16(Bp + 64 * C_ + (k0),  &Bsl[buf][64 + w * 16][0]);       \
  } while (0)

  STAGE_QKV(0, 0);
  __syncthreads();                       // vmcnt(0) drain: buf0 ready

  int cur = 0;
  for (int k0 = 0; k0 < C_; k0 += 32) {
    if (k0 + 32 < C_) STAGE_QKV(cur ^ 1, k0 + 32);
    bf16x8_t af[4], bfv[4];
    for (int i = 0; i < 4; ++i) af[i]  = *(bf16x8_t*)&Asl[cur][wm * 64 + i * 16 + lr][quad * 8];
    for (int j = 0; j < 4; ++j) bfv[j] = *(bf16x8_t*)&Bsl[cur][wn * 64 + j * 16 + lr][quad * 8];
    for (int i = 0; i < 4; ++i)
      for (int j = 0; j < 4; ++j)
        acc[i][j] = MFMA16(af[i], bfv[j], acc[i][j]);
    __syncthreads();                     // drains staged loads + frag reads
    cur ^= 1;
  }
#undef STAGE_QKV

  for (int i = 0; i < 4; ++i) {
    int ob = m0 + wm * 64 + i * 16 + quad * 4;
    int h = ob / 192, r0 = ob % 192;
    for (int j = 0; j < 4; ++j) {
      int t = n0 + wn * 64 + j * 16 + lr;
      if (r0 < 128) {
        unsigned short pk[4] __attribute__((aligned(8)));
      #pragma unroll
        for (int r = 0; r < 4; ++r) pk[r] = f2bf(acc[i][j][r] + bias[ob + r]);
        unsigned short* base = (r0 < 64) ? q_t : k_t;
        int chn = (r0 < 64) ? r0 : r0 - 64;
        *(uint2*)&base[((size_t)(b * NH_ + h) * T_ + t) * CH_ + chn] = *(uint2*)pk;
      } else {
      #pragma unroll
        for (int r = 0; r < 4; ++r) {
          float vv = acc[i][j][r] + bias[ob + r];
          v_c[((size_t)(b * NH_ + h) * CH_ + (r0 - 128 + r)) * T_ + t] = f2bf(vv);
        }
      }
    }
  }
}

// ---------------------------------------------------------------------------
// Flash attention v5: QBLK=256 (64 t-rows per wave). K/V-tile reads and
// staging amortize over 2x the rows vs QBLK=128: LDS bytes per wave-iter
// 28KB/32rows -> 36KB/64rows (-36% per row; total 917MB -> 590MB).
// K/V staged in LDS with register prefetch (R3-proven; no in-loop global
// loads -- R4's regression). Q frags loaded once from global before loop.
// Swapped QK^T (mfma(K,Q)), fixed-shift softmax, in-register row-sum,
// wave-local P roundtrip. LDS 54KB, grid 64x4=256 blocks = 1/CU.
// ---------------------------------------------------------------------------
__global__ __launch_bounds__(256) void attn_kernel(
    const unsigned short* __restrict__ q_t, const unsigned short* __restrict__ k_t,
    const unsigned short* __restrict__ v_c, unsigned short* __restrict__ a_t)
{
  int bh = blockIdx.x;
  int t0 = blockIdx.y * 256;
  int tid = threadIdx.x;
  int w = tid >> 6, lane = tid & 63, quad = lane >> 4, lr = lane & 15;

  __shared__ __align__(16) unsigned short k_s[64][72];
  __shared__ __align__(16) unsigned short v_s[64][72];
  __shared__ __align__(16) unsigned short p_s[256][72];  // P roundtrip + out stage

  int r0 = tid >> 3, c0 = (tid & 7) * 8;    // staging: 32 rows x 64 cols/chunk

  // Q fragments once from global: t = t0 + w*64 + rb*16 + lr, ch = kk*32+quad*8
  bf16x8_t bq[4][2];
#pragma unroll
  for (int rb = 0; rb < 4; ++rb)
#pragma unroll
    for (int kk = 0; kk < 2; ++kk)
      bq[rb][kk] = *(const bf16x8_t*)
          &q_t[((size_t)bh * T_ + t0 + w * 64 + rb * 16 + lr) * CH_ + kk * 32 + quad * 8];

  // prefetch K/V tile 0 (64 s-rows)
  uint4 kr0 = *(const uint4*)&k_t[((size_t)bh * T_ + r0) * CH_ + c0];
  uint4 kr1 = *(const uint4*)&k_t[((size_t)bh * T_ + r0 + 32) * CH_ + c0];
  uint4 vr0 = *(const uint4*)&v_c[((size_t)bh * CH_ + r0) * T_ + c0];
  uint4 vr1 = *(const uint4*)&v_c[((size_t)bh * CH_ + r0 + 32) * T_ + c0];

  f32x4_t o_acc[4][4];
#pragma unroll
  for (int rb = 0; rb < 4; ++rb)
    for (int j = 0; j < 4; ++j) o_acc[rb][j] = (f32x4_t){0.f, 0.f, 0.f, 0.f};
  float l_sum[4] = {0.f, 0.f, 0.f, 0.f};   // rowsum partials, t = w*64+rb*16+lr

  const float SCL = 0.18033688f;   // 0.125 * log2(e)
  const float MSH = 11.541560f;    // 8 * log2(e)  (fixed softmax shift)

  for (int s0 = 0; s0 < T_; s0 += 64) {
    __syncthreads();               // all reads of k_s/v_s from prev iter done
    *(uint4*)&k_s[r0][c0]      = kr0;
    *(uint4*)&k_s[r0 + 32][c0] = kr1;
    *(uint4*)&v_s[r0][c0]      = vr0;
    *(uint4*)&v_s[r0 + 32][c0] = vr1;
    if (s0 + 64 < T_) {
      kr0 = *(const uint4*)&k_t[((size_t)bh * T_ + s0 + 64 + r0) * CH_ + c0];
      kr1 = *(const uint4*)&k_t[((size_t)bh * T_ + s0 + 96 + r0) * CH_ + c0];
      vr0 = *(const uint4*)&v_c[((size_t)bh * CH_ + r0) * T_ + s0 + 64 + c0];
      vr1 = *(const uint4*)&v_c[((size_t)bh * CH_ + r0 + 32) * T_ + s0 + 64 + c0];
    }
    __syncthreads();

    // Swapped QK^T + softmax per j (short live range):
    // C[s][t]: thread (quad,lr) holds s = j*16 + quad*4 + r, t = w*64+rb*16+lr
#pragma unroll
    for (int j = 0; j < 4; ++j) {
      bf16x8_t ak0 = *(bf16x8_t*)&k_s[j * 16 + lr][quad * 8];
      bf16x8_t ak1 = *(bf16x8_t*)&k_s[j * 16 + lr][32 + quad * 8];
      f32x4_t av[4];
#pragma unroll
      for (int rb = 0; rb < 4; ++rb) {
        f32x4_t a = (f32x4_t){0.f, 0.f, 0.f, 0.f};
        a = MFMA16(ak0, bq[rb][0], a);
        a = MFMA16(ak1, bq[rb][1], a);
        av[rb] = a;
      }
#pragma unroll
      for (int rb = 0; rb < 4; ++rb) {
        unsigned u[4];
        float rsum = 0.f;
#pragma unroll
        for (int r = 0; r < 4; ++r) {
          union { float f; unsigned v; } cv;
          cv.f = __builtin_amdgcn_exp2f(av[rb][r] * SCL - MSH);
          u[r] = cv.v & 0xFFFF0000u;             // truncated-bf16 as fp32 bits
          union { unsigned v; float f; } rf; rf.v = u[r];
          rsum += rf.f;
        }
        uint2 pk;
        pk.x = (u[0] >> 16) | u[1];
        pk.y = (u[2] >> 16) | u[3];
        *(uint2*)&p_s[w * 64 + rb * 16 + lr][j * 16 + quad * 4] = pk;
        l_sum[rb] += rsum;
      }
    }

    // wave-local roundtrip: wave w wrote rows w*64..w*64+63, reads the same
    bf16x8_t ap[4][2];
#pragma unroll
    for (int rb = 0; rb < 4; ++rb) {
      ap[rb][0] = *(bf16x8_t*)&p_s[w * 64 + rb * 16 + lr][quad * 8];
      ap[rb][1] = *(bf16x8_t*)&p_s[w * 64 + rb * 16 + lr][32 + quad * 8];
    }

    __builtin_amdgcn_s_setprio(1);
#pragma unroll
    for (int j = 0; j < 4; ++j) {
      bf16x8_t bv0 = *(bf16x8_t*)&v_s[j * 16 + lr][quad * 8];
      bf16x8_t bv1 = *(bf16x8_t*)&v_s[j * 16 + lr][32 + quad * 8];
#pragma unroll
      for (int rb = 0; rb < 4; ++rb) {
        o_acc[rb][j] = MFMA16(ap[rb][0], bv0, o_acc[rb][j]);
        o_acc[rb][j] = MFMA16(ap[rb][1], bv1, o_acc[rb][j]);
      }
    }
    __builtin_amdgcn_s_setprio(0);
  }

  // final rowsum reduce over quads (bits 4,5 of lane): per-thread partial
  // covers s = {16j + quad*4 + r}; quad-reduce completes the row.
#pragma unroll
  for (int rb = 0; rb < 4; ++rb) {
    l_sum[rb] += __shfl_xor(l_sum[rb], 16, 64);
    l_sum[rb] += __shfl_xor(l_sum[rb], 32, 64);
  }

  // normalize + stage output via p_s (reuse, wave-local rows), then store
#pragma unroll
  for (int rb = 0; rb < 4; ++rb) {
#pragma unroll
    for (int r = 0; r < 4; ++r) {
      float lv = __shfl(l_sum[rb], quad * 4 + r, 64);
      float inv = 1.f / lv;
#pragma unroll
      for (int j = 0; j < 4; ++j)
        p_s[w * 64 + rb * 16 + quad * 4 + r][j * 16 + lr] = f2bf(o_acc[rb][j][r] * inv);
    }
  }
  __syncthreads();
#pragma unroll
  for (int cch = 0; cch < 8; ++cch)
    *(uint4*)&a_t[((size_t)bh * T_ + t0 + r0 + 32 * cch) * CH_ + c0] =
        *(uint4*)&p_s[r0 + 32 * cch][c0];
}

// ---------------------------------------------------------------------------
// Proj GEMM (bf16 MFMA) + bias + fp32 residual -> d_out [b][o][t]
// global_load_lds staging, 2-phase dbuf, 1 barrier/K.
// ---------------------------------------------------------------------------
__global__ __launch_bounds__(256) void gemm_proj_kernel(
    const unsigned short* __restrict__ W, const unsigned short* __restrict__ a_t,
    const float* __restrict__ bias, const float* __restrict__ xres,
    float* __restrict__ out)
{
  int b = blockIdx.z;
  int m0 = blockIdx.y * 128, n0 = blockIdx.x * 128;
  int tid = threadIdx.x;
  int w = tid >> 6, lane = tid & 63, quad = lane >> 4, lr = lane & 15;
  int wm = w >> 1, wn = w & 1;

  __shared__ __align__(16) unsigned short Asl[2][128][32];
  __shared__ __align__(16) unsigned short Bsl[2][128][32];

  f32x4_t acc[4][4];
  for (int i = 0; i < 4; ++i)
    for (int j = 0; j < 4; ++j) acc[i][j] = (f32x4_t){0.f, 0.f, 0.f, 0.f};

  int ur = tid >> 2, uk = (tid & 3) * 8;
  const unsigned short* Ap = W + (size_t)(m0 + ur) * C_ + uk;

#define STAGE_PROJ(buf, k0)                                                   \
  do {                                                                        \
    const unsigned short* Bp = a_t +                                          \
        ((size_t)(b * NH_ + ((k0) >> 6)) * T_ + n0 + ur) * CH_ + ((k0) & 63) + uk; \
    GLD16(Ap + (k0),           &Asl[buf][w * 16][0]);                         \
    GLD16(Ap + 64 * C_ + (k0), &Asl[buf][64 + w * 16][0]);                    \
    GLD16(Bp,                  &Bsl[buf][w * 16][0]);                         \
    GLD16(Bp + 64 * CH_,       &Bsl[buf][64 + w * 16][0]);                    \
  } while (0)

  STAGE_PROJ(0, 0);
  __syncthreads();

  int cur = 0;
  for (int k0 = 0; k0 < C_; k0 += 32) {
    if (k0 + 32 < C_) STAGE_PROJ(cur ^ 1, k0 + 32);
    bf16x8_t af[4], bfv[4];
    for (int i = 0; i < 4; ++i) af[i]  = *(bf16x8_t*)&Asl[cur][wm * 64 + i * 16 + lr][quad * 8];
    for (int j = 0; j < 4; ++j) bfv[j] = *(bf16x8_t*)&Bsl[cur][wn * 64 + j * 16 + lr][quad * 8];
    for (int i = 0; i < 4; ++i)
      for (int j = 0; j < 4; ++j)
        acc[i][j] = MFMA16(af[i], bfv[j], acc[i][j]);
    __syncthreads();
    cur ^= 1;
  }
#undef STAGE_PROJ

  for (int i = 0; i < 4; ++i) {
    int ob = m0 + wm * 64 + i * 16 + quad * 4;
    for (int j = 0; j < 4; ++j) {
      int t = n0 + wn * 64 + j * 16 + lr;
    #pragma unroll
      for (int r = 0; r < 4; ++r) {
        size_t idx = ((size_t)(b * C_ + ob + r)) * T_ + t;
        out[idx] = acc[i][j][r] + bias[ob + r] + xres[idx];
      }
    }
  }
}

// ---------------------------------------------------------------------------
extern "C" void kernel_launch(void* const* d_in, const int* in_sizes, int n_in,
                              void* d_out, int out_size, void* d_ws, size_t ws_size,
                              hipStream_t stream)
{
  const float* x      = (const float*)d_in[0];
  const float* norm_w = (const float*)d_in[1];
  const float* norm_b = (const float*)d_in[2];
  const float* qkv_w  = (const float*)d_in[3];
  const float* qkv_b  = (const float*)d_in[4];
  const float* proj_w = (const float*)d_in[5];
  const float* proj_b = (const float*)d_in[6];
  float* out = (float*)d_out;

  char* ws = (char*)d_ws;
  unsigned short* qw  = (unsigned short*)ws;                       // 1.5 MiB
  unsigned short* pw  = (unsigned short*)(ws + 1572864);           // 0.5 MiB
  unsigned short* xnT = (unsigned short*)(ws + 2097152);           // 8 MiB
  unsigned short* q_t = (unsigned short*)(ws + 10485760);          // 8 MiB
  unsigned short* k_t = (unsigned short*)(ws + 18874368);          // 8 MiB
  unsigned short* v_c = (unsigned short*)(ws + 27262976);          // 8 MiB
  unsigned short* a_t = (unsigned short*)(ws + 35651584);          // 8 MiB

  prep_gn_kernel<<<dim3(256 + 1024), dim3(256), 0, stream>>>(
      x, norm_w, norm_b, xnT, qkv_w, proj_w, qw, pw);

  gemm_qkv_kernel<<<dim3(T_ / 128, 1536 / 128, B_), dim3(256), 0, stream>>>(
      qw, xnT, qkv_b, q_t, k_t, v_c);

  attn_kernel<<<dim3(B_ * NH_, T_ / 256), dim3(256), 0, stream>>>(q_t, k_t, v_c, a_t);

  gemm_proj_kernel<<<dim3(T_ / 128, C_ / 128, B_), dim3(256), 0, stream>>>(
      pw, a_t, proj_b, x, out);
}

// Round 6
// 149.770 us; speedup vs baseline: 1.1146x; 1.0988x over previous
//
#include <hip/hip_runtime.h>
#include <math.h>

typedef float f32x4_t __attribute__((ext_vector_type(4)));
typedef short bf16x8_t __attribute__((ext_vector_type(8)));

#define B_   8
#define C_   512
#define T_   1024
#define NH_  8
#define CH_  64
#define EPSF 1e-5f

#define MFMA16(a, b, c) __builtin_amdgcn_mfma_f32_16x16x32_bf16((a), (b), (c), 0, 0, 0)

// Direct global->LDS 16B copy. LDS dest is wave-uniform base + lane*16.
#define GLD16(gp, lp) __builtin_amdgcn_global_load_lds( \
    (const __attribute__((address_space(1))) unsigned int*)(gp), \
    (__attribute__((address_space(3))) unsigned int*)(lp), 16, 0, 0)

__device__ __forceinline__ unsigned short f2bf(float f) {
  union { float f; unsigned u; } v; v.f = f;
  unsigned r = v.u + 0x7FFFu + ((v.u >> 16) & 1u);
  return (unsigned short)(r >> 16);
}

// ---------------------------------------------------------------------------
// Fused: blocks 0..255 do GroupNorm -> xnT[b][t][c] bf16; blocks 256.. do
// fp32->bf16 weight conversion. GN stages the 64KB group slice in LDS during
// the sum pass so x is read from HBM exactly once.
// ---------------------------------------------------------------------------
__global__ __launch_bounds__(256) void prep_gn_kernel(
    const float* __restrict__ x, const float* __restrict__ w,
    const float* __restrict__ bvec, unsigned short* __restrict__ xnT,
    const float* __restrict__ qw_f, const float* __restrict__ pw_f,
    unsigned short* __restrict__ qw, unsigned short* __restrict__ pw)
{
  __shared__ __align__(16) float xs[16 * 1024];   // 64 KB group slice
  __shared__ float rs_[4], r2_[4];
  __shared__ float mu_s, rsig_s;

  int tid = threadIdx.x;
  if (blockIdx.x >= 256) {
    int idx = (blockIdx.x - 256) * 256 + tid;    // float4 granularity
    const int N1 = 1536 * 512 / 4;
    const int N2 = 512 * 512 / 4;
    if (idx < N1) {
      float4 v = ((const float4*)qw_f)[idx];
      uint2 o;
      o.x = (unsigned)f2bf(v.x) | ((unsigned)f2bf(v.y) << 16);
      o.y = (unsigned)f2bf(v.z) | ((unsigned)f2bf(v.w) << 16);
      ((uint2*)qw)[idx] = o;
    } else if (idx < N1 + N2) {
      int j = idx - N1;
      float4 v = ((const float4*)pw_f)[j];
      uint2 o;
      o.x = (unsigned)f2bf(v.x) | ((unsigned)f2bf(v.y) << 16);
      o.y = (unsigned)f2bf(v.z) | ((unsigned)f2bf(v.w) << 16);
      ((uint2*)pw)[j] = o;
    }
    return;
  }

  int blk = blockIdx.x;            // b*32 + g
  int b = blk >> 5, g = blk & 31;
  const float* xp = x + ((size_t)(b * C_ + g * 16)) * T_;
  const int N = 16 * T_;           // 16384

  float s = 0.f, s2 = 0.f;
  for (int i = tid * 4; i < N; i += 256 * 4) {
    float4 v = *(const float4*)(xp + i);
    *(float4*)&xs[i] = v;                          // stash for pass 2
    s  += v.x + v.y + v.z + v.w;
    s2 += v.x * v.x + v.y * v.y + v.z * v.z + v.w * v.w;
  }
  for (int off = 32; off; off >>= 1) {
    s  += __shfl_down(s,  off, 64);
    s2 += __shfl_down(s2, off, 64);
  }
  int wid = tid >> 6, lane = tid & 63;
  if (lane == 0) { rs_[wid] = s; r2_[wid] = s2; }
  __syncthreads();
  if (tid == 0) {
    float ts = rs_[0] + rs_[1] + rs_[2] + rs_[3];
    float t2 = r2_[0] + r2_[1] + r2_[2] + r2_[3];
    float mu = ts / (float)N;
    float var = t2 / (float)N - mu * mu;
    mu_s = mu;
    rsig_s = rsqrtf(var + EPSF);
  }
  __syncthreads();
  float mu = mu_s, rs = rsig_s;

  float wl[16], bl[16];
  for (int c = 0; c < 16; ++c) { wl[c] = w[g * 16 + c]; bl[c] = bvec[g * 16 + c]; }

  for (int t = tid; t < T_; t += 256) {
    unsigned short buf[16] __attribute__((aligned(16)));
    for (int c = 0; c < 16; ++c) {
      float val = xs[c * T_ + t];                  // LDS, conflict-free
      buf[c] = f2bf((val - mu) * rs * wl[c] + bl[c]);
    }
    unsigned short* dst = xnT + ((size_t)b * T_ + t) * C_ + g * 16;
    *(uint4*)dst       = *(uint4*)buf;
    *(uint4*)(dst + 8) = *(uint4*)(buf + 8);
  }
}

// ---------------------------------------------------------------------------
// QKV GEMM (bf16 MFMA): 3-buffer counted-vmcnt K-loop (T4). Loads for tile
// t+1/t+2 stay IN FLIGHT across the barrier (vmcnt(4), never 0 until the
// last iter). Raw s_barrier + asm waitcnt per the m201/m218 template.
// Safety: each wave stages its own rows -> own vmcnt(4) + barrier = tile
// ready; buffer overwritten at iter t was read at t-1, and those ds_reads
// are consumed by MFMAs (lgkmcnt) before the barrier.
// ---------------------------------------------------------------------------
__global__ __launch_bounds__(256) void gemm_qkv_kernel(
    const unsigned short* __restrict__ W, const unsigned short* __restrict__ xnT,
    const float* __restrict__ bias,
    unsigned short* __restrict__ q_t, unsigned short* __restrict__ k_t,
    unsigned short* __restrict__ v_c)
{
  int b = blockIdx.z;
  int m0 = blockIdx.y * 128, n0 = blockIdx.x * 128;
  int tid = threadIdx.x;
  int w = tid >> 6, lane = tid & 63, quad = lane >> 4, lr = lane & 15;
  int wm = w >> 1, wn = w & 1;

  __shared__ __align__(16) unsigned short Asl[3][128][32];
  __shared__ __align__(16) unsigned short Bsl[3][128][32];

  f32x4_t acc[4][4];
  for (int i = 0; i < 4; ++i)
    for (int j = 0; j < 4; ++j) acc[i][j] = (f32x4_t){0.f, 0.f, 0.f, 0.f};

  int ur = tid >> 2, uk = (tid & 3) * 8;
  const unsigned short* Ap = W + (size_t)(m0 + ur) * C_ + uk;
  const unsigned short* Bp = xnT + ((size_t)b * T_ + n0 + ur) * C_ + uk;

#define STAGE_QKV(buf, k0)                                        \
  do {                                                            \
    GLD16(Ap + (k0),            &Asl[buf][w * 16][0]);            \
    GLD16(Ap + 64 * C_ + (k0),  &Asl[buf][64 + w * 16][0]);       \
    GLD16(Bp + (k0),            &Bsl[buf][w * 16][0]);            \
    GLD16(Bp + 64 * C_ + (k0),  &Bsl[buf][64 + w * 16][0]);       \
  } while (0)

  STAGE_QKV(0, 0);
  STAGE_QKV(1, 32);

  for (int it = 0; it < 16; ++it) {
    if (it < 15) asm volatile("s_waitcnt vmcnt(4)" ::: "memory");
    else         asm volatile("s_waitcnt vmcnt(0)" ::: "memory");
    __builtin_amdgcn_s_barrier();
    __builtin_amdgcn_sched_barrier(0);
    if (it + 2 < 16) STAGE_QKV((it + 2) % 3, (it + 2) * 32);
    int cur = it % 3;
    bf16x8_t af[4], bfv[4];
    for (int i = 0; i < 4; ++i) af[i]  = *(bf16x8_t*)&Asl[cur][wm * 64 + i * 16 + lr][quad * 8];
    for (int j = 0; j < 4; ++j) bfv[j] = *(bf16x8_t*)&Bsl[cur][wn * 64 + j * 16 + lr][quad * 8];
    for (int i = 0; i < 4; ++i)
      for (int j = 0; j < 4; ++j)
        acc[i][j] = MFMA16(af[i], bfv[j], acc[i][j]);
  }
#undef STAGE_QKV

  for (int i = 0; i < 4; ++i) {
    int ob = m0 + wm * 64 + i * 16 + quad * 4;
    int h = ob / 192, r0 = ob % 192;
    for (int j = 0; j < 4; ++j) {
      int t = n0 + wn * 64 + j * 16 + lr;
      if (r0 < 128) {
        unsigned short pk[4] __attribute__((aligned(8)));
      #pragma unroll
        for (int r = 0; r < 4; ++r) pk[r] = f2bf(acc[i][j][r] + bias[ob + r]);
        unsigned short* base = (r0 < 64) ? q_t : k_t;
        int chn = (r0 < 64) ? r0 : r0 - 64;
        *(uint2*)&base[((size_t)(b * NH_ + h) * T_ + t) * CH_ + chn] = *(uint2*)pk;
      } else {
      #pragma unroll
        for (int r = 0; r < 4; ++r) {
          float vv = acc[i][j][r] + bias[ob + r];
          v_c[((size_t)(b * NH_ + h) * CH_ + (r0 - 128 + r)) * T_ + t] = f2bf(vv);
        }
      }
    }
  }
}

// ---------------------------------------------------------------------------
// Flash attention (R3 version, best measured): QBLK=128, swapped QK^T
// (mfma(K,Q)) -> packed 8B P-stores, in-register row-sum, fixed-shift
// softmax, wave-local P roundtrip, register-prefetched K/V staging.
// ---------------------------------------------------------------------------
__global__ __launch_bounds__(256) void attn_kernel(
    const unsigned short* __restrict__ q_t, const unsigned short* __restrict__ k_t,
    const unsigned short* __restrict__ v_c, unsigned short* __restrict__ a_t)
{
  int bh = blockIdx.x;
  int t0 = blockIdx.y * 128;
  int tid = threadIdx.x;
  int w = tid >> 6, lane = tid & 63, quad = lane >> 4, lr = lane & 15;

  __shared__ __align__(16) unsigned short q_s[128][72];
  __shared__ __align__(16) unsigned short p_s[128][72];
  __shared__ __align__(16) unsigned short k_s[64][72];
  __shared__ __align__(16) unsigned short v_s[64][72];

  int r0 = tid >> 3, c0 = (tid & 7) * 8;    // 32 rows x 64 cols per chunk
  // stage Q tile [t][ch]: 4 chunks of 32 rows
#pragma unroll
  for (int cch = 0; cch < 4; ++cch)
    *(uint4*)&q_s[r0 + 32 * cch][c0] =
        *(const uint4*)&q_t[((size_t)bh * T_ + t0 + r0 + 32 * cch) * CH_ + c0];

  // prefetch K/V tile 0 (64 s-rows)
  uint4 kr0 = *(const uint4*)&k_t[((size_t)bh * T_ + r0) * CH_ + c0];
  uint4 kr1 = *(const uint4*)&k_t[((size_t)bh * T_ + r0 + 32) * CH_ + c0];
  uint4 vr0 = *(const uint4*)&v_c[((size_t)bh * CH_ + r0) * T_ + c0];
  uint4 vr1 = *(const uint4*)&v_c[((size_t)bh * CH_ + r0 + 32) * T_ + c0];

  __syncthreads();                 // q_s visible to all waves
  // wave w owns t-rows [w*32, w*32+32). Q as B-fragment: col t = lr,
  // k = ch = kk*32 + quad*8 + e.
  bf16x8_t bq[2][2];
#pragma unroll
  for (int rb = 0; rb < 2; ++rb) {
    bq[rb][0] = *(bf16x8_t*)&q_s[w * 32 + rb * 16 + lr][quad * 8];
    bq[rb][1] = *(bf16x8_t*)&q_s[w * 32 + rb * 16 + lr][32 + quad * 8];
  }

  f32x4_t o_acc[2][4];
#pragma unroll
  for (int rb = 0; rb < 2; ++rb)
    for (int j = 0; j < 4; ++j) o_acc[rb][j] = (f32x4_t){0.f, 0.f, 0.f, 0.f};
  float l_sum[2] = {0.f, 0.f};     // rowsum for t = w*32 + rb*16 + lr

  const float SCL = 0.18033688f;   // 0.125 * log2(e)
  const float MSH = 11.541560f;    // 8 * log2(e)  (fixed softmax shift)

  for (int s0 = 0; s0 < T_; s0 += 64) {
    __syncthreads();               // all reads of k_s/v_s from prev iter done
    *(uint4*)&k_s[r0][c0]      = kr0;
    *(uint4*)&k_s[r0 + 32][c0] = kr1;
    *(uint4*)&v_s[r0][c0]      = vr0;
    *(uint4*)&v_s[r0 + 32][c0] = vr1;
    if (s0 + 64 < T_) {
      kr0 = *(const uint4*)&k_t[((size_t)bh * T_ + s0 + 64 + r0) * CH_ + c0];
      kr1 = *(const uint4*)&k_t[((size_t)bh * T_ + s0 + 96 + r0) * CH_ + c0];
      vr0 = *(const uint4*)&v_c[((size_t)bh * CH_ + r0) * T_ + s0 + 64 + c0];
      vr1 = *(const uint4*)&v_c[((size_t)bh * CH_ + r0 + 32) * T_ + s0 + 64 + c0];
    }
    __syncthreads();

    // Swapped QK^T: C[s][t] = sum_ch K[s][ch] * Q[t][ch].
    // K as A-frag: row s = j*16 + lr, k = ch. Output: thread (quad,lr)
    // holds s = j*16 + quad*4 + r (4 consecutive s), t = rb*16 + lr.
    f32x4_t sc[4][2];
    __builtin_amdgcn_s_setprio(1);
#pragma unroll
    for (int j = 0; j < 4; ++j) {
      bf16x8_t ak0 = *(bf16x8_t*)&k_s[j * 16 + lr][quad * 8];
      bf16x8_t ak1 = *(bf16x8_t*)&k_s[j * 16 + lr][32 + quad * 8];
      f32x4_t a0 = (f32x4_t){0.f, 0.f, 0.f, 0.f};
      f32x4_t a1 = (f32x4_t){0.f, 0.f, 0.f, 0.f};
      a0 = MFMA16(ak0, bq[0][0], a0);
      a0 = MFMA16(ak1, bq[0][1], a0);
      a1 = MFMA16(ak0, bq[1][0], a1);
      a1 = MFMA16(ak1, bq[1][1], a1);
      sc[j][0] = a0;
      sc[j][1] = a1;
    }
    __builtin_amdgcn_s_setprio(0);

    // p = exp2(score*SCL - MSH), truncate to bf16. Thread's 4 values are
    // consecutive s for one t-row -> pack into one 8B LDS write.
#pragma unroll
    for (int rb = 0; rb < 2; ++rb) {
      float rsum = 0.f;
#pragma unroll
      for (int j = 0; j < 4; ++j) {
        unsigned u[4];
#pragma unroll
        for (int r = 0; r < 4; ++r) {
          union { float f; unsigned v; } cv;
          cv.f = __builtin_amdgcn_exp2f(sc[j][rb][r] * SCL - MSH);
          u[r] = cv.v & 0xFFFF0000u;             // truncated-bf16 as fp32 bits
          union { unsigned v; float f; } rf; rf.v = u[r];
          rsum += rf.f;
        }
        uint2 pk;
        pk.x = (u[0] >> 16) | u[1];
        pk.y = (u[2] >> 16) | u[3];
        *(uint2*)&p_s[w * 32 + rb * 16 + lr][j * 16 + quad * 4] = pk;
        rsum = rsum;
      }
      // NOTE: rsum accumulated per j inside the loop above
      // (recompute below to keep exact R3 semantics)
      (void)rsum;
    }
    // recompute rowsum partials exactly as R3 (per j, per rb)
#pragma unroll
    for (int rb = 0; rb < 2; ++rb) {
      float rsum = 0.f;
#pragma unroll
      for (int j = 0; j < 4; ++j) {
#pragma unroll
        for (int r = 0; r < 4; ++r) {
          union { float f; unsigned v; } cv;
          cv.f = __builtin_amdgcn_exp2f(sc[j][rb][r] * SCL - MSH);
          union { unsigned v; float f; } rf; rf.v = cv.v & 0xFFFF0000u;
          rsum += rf.f;
        }
      }
      rsum += __shfl_xor(rsum, 16, 64);
      rsum += __shfl_xor(rsum, 32, 64);
      l_sum[rb] += rsum;
    }

    // wave-local roundtrip: wave w wrote rows w*32..w*32+31, reads the same
    bf16x8_t ap[2][2];
#pragma unroll
    for (int rb = 0; rb < 2; ++rb) {
      ap[rb][0] = *(bf16x8_t*)&p_s[w * 32 + rb * 16 + lr][quad * 8];
      ap[rb][1] = *(bf16x8_t*)&p_s[w * 32 + rb * 16 + lr][32 + quad * 8];
    }

    __builtin_amdgcn_s_setprio(1);
#pragma unroll
    for (int j = 0; j < 4; ++j)
#pragma unroll
      for (int kk = 0; kk < 2; ++kk) {
        bf16x8_t bv = *(bf16x8_t*)&v_s[j * 16 + lr][kk * 32 + quad * 8];
        o_acc[0][j] = MFMA16(ap[0][kk], bv, o_acc[0][j]);
        o_acc[1][j] = MFMA16(ap[1][kk], bv, o_acc[1][j]);
      }
    __builtin_amdgcn_s_setprio(0);
  }

  // normalize: o_acc row t = w*32 + rb*16 + quad*4 + r needs l_sum held by
  // lane with lr = quad*4 + r (all quads hold identical reduced values).
#pragma unroll
  for (int rb = 0; rb < 2; ++rb) {
#pragma unroll
    for (int r = 0; r < 4; ++r) {
      float lv = __shfl(l_sum[rb], quad * 4 + r, 64);
      float inv = 1.f / lv;
#pragma unroll
      for (int j = 0; j < 4; ++j)
        q_s[w * 32 + rb * 16 + quad * 4 + r][j * 16 + lr] = f2bf(o_acc[rb][j][r] * inv);
    }
  }
  __syncthreads();
#pragma unroll
  for (int cch = 0; cch < 4; ++cch)
    *(uint4*)&a_t[((size_t)bh * T_ + t0 + r0 + 32 * cch) * CH_ + c0] =
        *(uint4*)&q_s[r0 + 32 * cch][c0];
}

// ---------------------------------------------------------------------------
// Proj GEMM (bf16 MFMA) + bias + fp32 residual -> d_out [b][o][t]
// 3-buffer counted-vmcnt K-loop (same template as gemm_qkv).
// ---------------------------------------------------------------------------
__global__ __launch_bounds__(256) void gemm_proj_kernel(
    const unsigned short* __restrict__ W, const unsigned short* __restrict__ a_t,
    const float* __restrict__ bias, const float* __restrict__ xres,
    float* __restrict__ out)
{
  int b = blockIdx.z;
  int m0 = blockIdx.y * 128, n0 = blockIdx.x * 128;
  int tid = threadIdx.x;
  int w = tid >> 6, lane = tid & 63, quad = lane >> 4, lr = lane & 15;
  int wm = w >> 1, wn = w & 1;

  __shared__ __align__(16) unsigned short Asl[3][128][32];
  __shared__ __align__(16) unsigned short Bsl[3][128][32];

  f32x4_t acc[4][4];
  for (int i = 0; i < 4; ++i)
    for (int j = 0; j < 4; ++j) acc[i][j] = (f32x4_t){0.f, 0.f, 0.f, 0.f};

  int ur = tid >> 2, uk = (tid & 3) * 8;
  const unsigned short* Ap = W + (size_t)(m0 + ur) * C_ + uk;

  // B rows are t (stride CH_ in a_t); k-column (head, ch) changes with k0:
  // head = k0>>6 (uniform), ch = (k0&32)+uk.
#define STAGE_PROJ(buf, k0)                                                   \
  do {                                                                        \
    const unsigned short* Bp = a_t +                                          \
        ((size_t)(b * NH_ + ((k0) >> 6)) * T_ + n0 + ur) * CH_ + ((k0) & 63) + uk; \
    GLD16(Ap + (k0),           &Asl[buf][w * 16][0]);                         \
    GLD16(Ap + 64 * C_ + (k0), &Asl[buf][64 + w * 16][0]);                    \
    GLD16(Bp,                  &Bsl[buf][w * 16][0]);                         \
    GLD16(Bp + 64 * CH_,       &Bsl[buf][64 + w * 16][0]);                    \
  } while (0)

  STAGE_PROJ(0, 0);
  STAGE_PROJ(1, 32);

  for (int it = 0; it < 16; ++it) {
    if (it < 15) asm volatile("s_waitcnt vmcnt(4)" ::: "memory");
    else         asm volatile("s_waitcnt vmcnt(0)" ::: "memory");
    __builtin_amdgcn_s_barrier();
    __builtin_amdgcn_sched_barrier(0);
    if (it + 2 < 16) STAGE_PROJ((it + 2) % 3, (it + 2) * 32);
    int cur = it % 3;
    bf16x8_t af[4], bfv[4];
    for (int i = 0; i < 4; ++i) af[i]  = *(bf16x8_t*)&Asl[cur][wm * 64 + i * 16 + lr][quad * 8];
    for (int j = 0; j < 4; ++j) bfv[j] = *(bf16x8_t*)&Bsl[cur][wn * 64 + j * 16 + lr][quad * 8];
    for (int i = 0; i < 4; ++i)
      for (int j = 0; j < 4; ++j)
        acc[i][j] = MFMA16(af[i], bfv[j], acc[i][j]);
  }
#undef STAGE_PROJ

  for (int i = 0; i < 4; ++i) {
    int ob = m0 + wm * 64 + i * 16 + quad * 4;
    for (int j = 0; j < 4; ++j) {
      int t = n0 + wn * 64 + j * 16 + lr;
    #pragma unroll
      for (int r = 0; r < 4; ++r) {
        size_t idx = ((size_t)(b * C_ + ob + r)) * T_ + t;
        out[idx] = acc[i][j][r] + bias[ob + r] + xres[idx];
      }
    }
  }
}

// ---------------------------------------------------------------------------
extern "C" void kernel_launch(void* const* d_in, const int* in_sizes, int n_in,
                              void* d_out, int out_size, void* d_ws, size_t ws_size,
                              hipStream_t stream)
{
  const float* x      = (const float*)d_in[0];
  const float* norm_w = (const float*)d_in[1];
  const float* norm_b = (const float*)d_in[2];
  const float* qkv_w  = (const float*)d_in[3];
  const float* qkv_b  = (const float*)d_in[4];
  const float* proj_w = (const float*)d_in[5];
  const float* proj_b = (const float*)d_in[6];
  float* out = (float*)d_out;

  char* ws = (char*)d_ws;
  unsigned short* qw  = (unsigned short*)ws;                       // 1.5 MiB
  unsigned short* pw  = (unsigned short*)(ws + 1572864);           // 0.5 MiB
  unsigned short* xnT = (unsigned short*)(ws + 2097152);           // 8 MiB
  unsigned short* q_t = (unsigned short*)(ws + 10485760);          // 8 MiB
  unsigned short* k_t = (unsigned short*)(ws + 18874368);          // 8 MiB
  unsigned short* v_c = (unsigned short*)(ws + 27262976);          // 8 MiB
  unsigned short* a_t = (unsigned short*)(ws + 35651584);          // 8 MiB

  prep_gn_kernel<<<dim3(256 + 1024), dim3(256), 0, stream>>>(
      x, norm_w, norm_b, xnT, qkv_w, proj_w, qw, pw);

  gemm_qkv_kernel<<<dim3(T_ / 128, 1536 / 128, B_), dim3(256), 0, stream>>>(
      qw, xnT, qkv_b, q_t, k_t, v_c);

  attn_kernel<<<dim3(B_ * NH_, T_ / 128), dim3(256), 0, stream>>>(q_t, k_t, v_c, a_t);

  gemm_proj_kernel<<<dim3(T_ / 128, C_ / 128, B_), dim3(256), 0, stream>>>(
      pw, a_t, proj_b, x, out);
}